// Round 10
// baseline (273.834 us; speedup 1.0000x reference)
//
#include <hip/hip_runtime.h>
#include <hip/hip_bf16.h>

#define NN 100000   // nodes
#define FF 10       // input features
#define HH 20       // hidden dim
#define GG 512      // graphs
#define LL 2        // labels

#define NB 500      // dst buckets
#define BNODES 200  // nodes per bucket (NN / NB)
#define CAP 7168    // per-bucket capacity (mean 6400, sigma ~80 -> 9.6 sigma)
#define STASH 14    // CAP / 512
#define TILE 4096   // edges per block in multisplit
#define SRC_BITS 17
#define SRC_MASK 0x1FFFFu

// bf16 helpers (storage-only; all math in f32)
__device__ inline unsigned short f2bf(float f) {
  unsigned u = __float_as_uint(f);
  unsigned r = u + 0x7FFFu + ((u >> 16) & 1u);
  return (unsigned short)(r >> 16);
}
__device__ inline float bflo(unsigned u) { return __uint_as_float(u << 16); }
__device__ inline float bfhi(unsigned u) { return __uint_as_float(u & 0xFFFF0000u); }

// ---------------------------------------------------------------------------
// Multisplit with LDS-staged COALESCED writes into fixed-CAP bucket regions.
// Payload pack: (local_dst << 17) | src.
// ---------------------------------------------------------------------------
__global__ __launch_bounds__(256) void multisplit_kernel(
    const int* __restrict__ src, const int* __restrict__ dst,
    int* __restrict__ cursor, unsigned int* __restrict__ pay, int E) {
  __shared__ int lhist[NB];
  __shared__ int lofs[NB];
  __shared__ int gbase[NB];
  __shared__ int lcur[NB];
  __shared__ unsigned int sord[TILE];
  __shared__ unsigned short sdbk[TILE];
  __shared__ int ss[512];
  int t = threadIdx.x;
  for (int i = t; i < NB; i += 256) lhist[i] = 0;
  __syncthreads();

  int base = blockIdx.x * TILE;
  int count = E - base;
  if (count > TILE) count = TILE;

  for (int i = t; i < count; i += 256)
    atomicAdd(&lhist[dst[base + i] / BNODES], 1);
  __syncthreads();

  // exclusive scan of lhist (NB=500) with 256 threads x 2 elements
  int own0 = (t < NB) ? lhist[t] : 0;
  int own1 = (t + 256 < NB) ? lhist[t + 256] : 0;
  ss[t] = own0;
  ss[t + 256] = own1;
  __syncthreads();
  for (int off = 1; off < 512; off <<= 1) {
    int a0 = (t >= off) ? ss[t - off] : 0;
    int a1 = (t + 256 >= off) ? ss[t + 256 - off] : 0;
    __syncthreads();
    ss[t] += a0;
    ss[t + 256] += a1;
    __syncthreads();
  }
  // reserve global ranges (clamped: >9-sigma overflow drops edges, no OOB)
  if (t < NB) {
    lofs[t] = ss[t] - own0;
    int bo = own0 ? atomicAdd(&cursor[t], own0) : 0;
    if (bo > CAP - own0) bo = CAP - own0;
    gbase[t] = t * CAP + bo;
    lcur[t] = 0;
  }
  if (t + 256 < NB) {
    lofs[t + 256] = ss[t + 256] - own1;
    int bo = own1 ? atomicAdd(&cursor[t + 256], own1) : 0;
    if (bo > CAP - own1) bo = CAP - own1;
    gbase[t + 256] = (t + 256) * CAP + bo;
    lcur[t + 256] = 0;
  }
  __syncthreads();

  // pass 2: rank + scatter into bucket-grouped LDS order
  for (int i = t; i < count; i += 256) {
    int e = base + i;
    int d = __builtin_nontemporal_load(dst + e);
    int s = __builtin_nontemporal_load(src + e);
    int bk = d / BNODES;
    int ld = d - bk * BNODES;
    int r = atomicAdd(&lcur[bk], 1);
    int slot = lofs[bk] + r;
    sord[slot] = ((unsigned)ld << SRC_BITS) | (unsigned)s;
    sdbk[slot] = (unsigned short)bk;
  }
  __syncthreads();

  // coalesced run writes
  for (int i = t; i < count; i += 256) {
    int bk = sdbk[i];
    pay[gbase[bk] + (i - lofs[bk])] = sord[i];
  }
}

// ---------------------------------------------------------------------------
// Fused bucket layer, register-accumulated, PAIR-INTERLEAVED gather:
//  A) stash pay run in registers; build block-local CSR in LDS
//  B) thread t<500 owns tasks (lnA=t/5, c) and (lnB=lnA+100, c); one fused
//     loop issues both nodes' loads per iteration (2x MLP), unroll 2 -> ~4
//     outstanding loads; VGPR accumulate; plain LDS stores into padded acc
//  C) dense + bias + root + ReLU from LDS -> bf16 hout
// F32IN: input rows are f32 (layer 1 reads x directly, no cast kernel).
// ---------------------------------------------------------------------------
template<int DIN, bool F32IN>
__global__ __launch_bounds__(512) void bucket_layer_kernel(
    const void* __restrict__ hin_v, const unsigned int* __restrict__ pay,
    const int* __restrict__ cursor, const float* __restrict__ Wrel,
    const float* __restrict__ bias, const float* __restrict__ Wroot,
    unsigned short* __restrict__ hout) {
  constexpr int AST = (DIN == 10) ? 11 : 21;  // padded acc stride
  constexpr int CH = DIN / 5;                 // features per chunk (2 or 4)
  __shared__ int sSrc[CAP];
  __shared__ float acc[BNODES * AST];
  __shared__ float rootsF[F32IN ? BNODES * DIN : 1];
  __shared__ unsigned short rootsB[F32IN ? 1 : BNODES * DIN];
  __shared__ float sWrel[DIN * HH];
  __shared__ float sWroot[DIN * HH];
  __shared__ float sb[HH];
  __shared__ int lhist[BNODES];
  __shared__ int lcur[BNODES];
  __shared__ int sRofs[BNODES];
  __shared__ int sRend[BNODES];
  __shared__ int ss[256];
  const float* hinF = (const float*)hin_v;
  const unsigned short* hinB = (const unsigned short*)hin_v;
  int b = blockIdx.x;
  int t = threadIdx.x;
  int nbase = b * BNODES;

  for (int i = t; i < DIN * HH; i += 512) {
    sWrel[i] = Wrel[i];
    sWroot[i] = Wroot[i];
  }
  if (t < HH) sb[t] = bias[t];
  if (t < BNODES) lhist[t] = 0;
  if (F32IN) {
    const float* rs = hinF + (size_t)nbase * DIN;
    for (int i = t; i < BNODES * DIN; i += 512) rootsF[i] = rs[i];
  } else {
    const unsigned* rs = (const unsigned*)(hinB + (size_t)nbase * DIN);
    unsigned* rd = (unsigned*)rootsB;
    for (int i = t; i < BNODES * DIN / 2; i += 512) rd[i] = rs[i];
  }
  __syncthreads();

  int ecnt = cursor[b];
  if (ecnt > CAP) ecnt = CAP;
  const unsigned int* mypay = pay + (size_t)b * CAP;

  // A1: stash + histogram
  unsigned ps[STASH];
#pragma unroll
  for (int u = 0; u < STASH; u++) {
    int i = t + u * 512;
    if (i < ecnt) {
      unsigned p = mypay[i];
      ps[u] = p;
      atomicAdd(&lhist[p >> SRC_BITS], 1);
    }
  }
  __syncthreads();

  // A2: scan (200 entries, first 256 threads)
  int own = (t < BNODES) ? lhist[t] : 0;
  if (t < 256) ss[t] = own;
  __syncthreads();
  for (int off = 1; off < 256; off <<= 1) {
    int a0 = (t < 256 && t >= off) ? ss[t - off] : 0;
    __syncthreads();
    if (t < 256) ss[t] += a0;
    __syncthreads();
  }
  if (t < BNODES) {
    int ex = ss[t] - own;
    sRofs[t] = ex;
    sRend[t] = ex + own;
    lcur[t] = 0;
  }
  __syncthreads();

  // A3: scatter src into node-sorted LDS order
#pragma unroll
  for (int u = 0; u < STASH; u++) {
    int i = t + u * 512;
    if (i < ecnt) {
      unsigned p = ps[u];
      int ld = p >> SRC_BITS;
      int r = atomicAdd(&lcur[ld], 1);
      sSrc[sRofs[ld] + r] = (int)(p & SRC_MASK);
    }
  }
  __syncthreads();

  // B: pair-interleaved gather with register accumulation
  if (t < 500) {
    int lnA = t / 5;
    int c = t - lnA * 5;
    int lnB = lnA + 100;
    int kA = sRofs[lnA], eA = sRend[lnA];
    int kB = sRofs[lnB], eB = sRend[lnB];
    int lenA = eA - kA, lenB = eB - kB;
    int m = lenA < lenB ? lenA : lenB;
    float a0A = 0, a1A = 0, a2A = 0, a3A = 0;
    float a0B = 0, a1B = 0, a2B = 0, a3B = 0;
    if (F32IN) {
      const float* xb = hinF + c * CH;
#pragma unroll 2
      for (int i = 0; i < m; i++) {
        int sA = sSrc[kA + i];
        int sB = sSrc[kB + i];
        float2 vA = *(const float2*)(xb + (size_t)sA * DIN);
        float2 vB = *(const float2*)(xb + (size_t)sB * DIN);
        a0A += vA.x; a1A += vA.y;
        a0B += vB.x; a1B += vB.y;
      }
      for (int i = m; i < lenA; i++) {
        float2 v = *(const float2*)(xb + (size_t)sSrc[kA + i] * DIN);
        a0A += v.x; a1A += v.y;
      }
      for (int i = m; i < lenB; i++) {
        float2 v = *(const float2*)(xb + (size_t)sSrc[kB + i] * DIN);
        a0B += v.x; a1B += v.y;
      }
    } else {
      const unsigned short* xb = hinB + c * CH;
#pragma unroll 2
      for (int i = 0; i < m; i++) {
        int sA = sSrc[kA + i];
        int sB = sSrc[kB + i];
        uint2 uA = *(const uint2*)(xb + (size_t)sA * DIN);
        uint2 uB = *(const uint2*)(xb + (size_t)sB * DIN);
        a0A += bflo(uA.x); a1A += bfhi(uA.x);
        a2A += bflo(uA.y); a3A += bfhi(uA.y);
        a0B += bflo(uB.x); a1B += bfhi(uB.x);
        a2B += bflo(uB.y); a3B += bfhi(uB.y);
      }
      for (int i = m; i < lenA; i++) {
        uint2 u = *(const uint2*)(xb + (size_t)sSrc[kA + i] * DIN);
        a0A += bflo(u.x); a1A += bfhi(u.x);
        a2A += bflo(u.y); a3A += bfhi(u.y);
      }
      for (int i = m; i < lenB; i++) {
        uint2 u = *(const uint2*)(xb + (size_t)sSrc[kB + i] * DIN);
        a0B += bflo(u.x); a1B += bfhi(u.x);
        a2B += bflo(u.y); a3B += bfhi(u.y);
      }
    }
    float* aA = acc + lnA * AST + c * CH;
    float* aB = acc + lnB * AST + c * CH;
    if (CH == 4) {
      aA[0] = a0A; aA[1] = a1A; aA[2] = a2A; aA[3] = a3A;
      aB[0] = a0B; aB[1] = a1B; aB[2] = a2B; aB[3] = a3B;
    } else {
      aA[0] = a0A; aA[1] = a1A;
      aB[0] = a0B; aB[1] = a1B;
    }
  }
  __syncthreads();

  // C: dense + bias + root + relu -> global bf16
  for (int idx = t; idx < BNODES * HH; idx += 512) {
    int ln = idx / HH;
    int j = idx - ln * HH;
    const float* a = acc + ln * AST;
    float v = sb[j];
#pragma unroll
    for (int f = 0; f < DIN; f++) {
      float rv = F32IN ? rootsF[ln * DIN + f] : bflo((unsigned)rootsB[ln * DIN + f]);
      v += a[f] * sWrel[f * HH + j];
      v += rv * sWroot[f * HH + j];
    }
    hout[(size_t)nbase * HH + idx] = f2bf(fmaxf(v, 0.0f));
  }
}

// ---------------------------------------------------------------------------
// Layer 3 + pooling: same pair-interleaved gather; dense staged in registers
// then written over acc (dead), then block-local pool + few global atomics.
// Post-ReLU >= 0 -> int atomicMax on float bits order-correct; zero init
// reproduces where(cnt>0, max, 0).
// ---------------------------------------------------------------------------
__global__ __launch_bounds__(512) void bucket_layer_pool_kernel(
    const unsigned short* __restrict__ hin, const unsigned int* __restrict__ pay,
    const int* __restrict__ cursor, const float* __restrict__ Wrel,
    const float* __restrict__ bias, const float* __restrict__ Wroot,
    const int* __restrict__ batch, float* __restrict__ sump,
    int* __restrict__ maxp, float* __restrict__ cnt) {
  constexpr int DIN = 20;
  constexpr int AST = 21;
  __shared__ int sSrc[CAP];
  __shared__ float acc[BNODES * AST];
  __shared__ unsigned short roots[BNODES * DIN];
  __shared__ int sBatch[BNODES];
  __shared__ float sWrel[DIN * HH];
  __shared__ float sWroot[DIN * HH];
  __shared__ float sb[HH];
  __shared__ int lhist[BNODES];
  __shared__ int lcur[BNODES];
  __shared__ int sRofs[BNODES];
  __shared__ int sRend[BNODES];
  __shared__ int ss[256];
  int b = blockIdx.x;
  int t = threadIdx.x;
  int nbase = b * BNODES;

  for (int i = t; i < DIN * HH; i += 512) {
    sWrel[i] = Wrel[i];
    sWroot[i] = Wroot[i];
  }
  if (t < HH) sb[t] = bias[t];
  if (t < BNODES) {
    lhist[t] = 0;
    sBatch[t] = batch[nbase + t];
  }
  {
    const unsigned* rs = (const unsigned*)(hin + (size_t)nbase * DIN);
    unsigned* rd = (unsigned*)roots;
    for (int i = t; i < BNODES * DIN / 2; i += 512) rd[i] = rs[i];
  }
  __syncthreads();

  int ecnt = cursor[b];
  if (ecnt > CAP) ecnt = CAP;
  const unsigned int* mypay = pay + (size_t)b * CAP;

  unsigned ps[STASH];
#pragma unroll
  for (int u = 0; u < STASH; u++) {
    int i = t + u * 512;
    if (i < ecnt) {
      unsigned p = mypay[i];
      ps[u] = p;
      atomicAdd(&lhist[p >> SRC_BITS], 1);
    }
  }
  __syncthreads();

  int own = (t < BNODES) ? lhist[t] : 0;
  if (t < 256) ss[t] = own;
  __syncthreads();
  for (int off = 1; off < 256; off <<= 1) {
    int a0 = (t < 256 && t >= off) ? ss[t - off] : 0;
    __syncthreads();
    if (t < 256) ss[t] += a0;
    __syncthreads();
  }
  if (t < BNODES) {
    int ex = ss[t] - own;
    sRofs[t] = ex;
    sRend[t] = ex + own;
    lcur[t] = 0;
  }
  __syncthreads();

#pragma unroll
  for (int u = 0; u < STASH; u++) {
    int i = t + u * 512;
    if (i < ecnt) {
      unsigned p = ps[u];
      int ld = p >> SRC_BITS;
      int r = atomicAdd(&lcur[ld], 1);
      sSrc[sRofs[ld] + r] = (int)(p & SRC_MASK);
    }
  }
  __syncthreads();

  if (t < 500) {
    int lnA = t / 5;
    int c = t - lnA * 5;
    int lnB = lnA + 100;
    int kA = sRofs[lnA], eA = sRend[lnA];
    int kB = sRofs[lnB], eB = sRend[lnB];
    int lenA = eA - kA, lenB = eB - kB;
    int m = lenA < lenB ? lenA : lenB;
    float a0A = 0, a1A = 0, a2A = 0, a3A = 0;
    float a0B = 0, a1B = 0, a2B = 0, a3B = 0;
    const unsigned short* xb = hin + c * 4;
#pragma unroll 2
    for (int i = 0; i < m; i++) {
      int sA = sSrc[kA + i];
      int sB = sSrc[kB + i];
      uint2 uA = *(const uint2*)(xb + (size_t)sA * 20);
      uint2 uB = *(const uint2*)(xb + (size_t)sB * 20);
      a0A += bflo(uA.x); a1A += bfhi(uA.x);
      a2A += bflo(uA.y); a3A += bfhi(uA.y);
      a0B += bflo(uB.x); a1B += bfhi(uB.x);
      a2B += bflo(uB.y); a3B += bfhi(uB.y);
    }
    for (int i = m; i < lenA; i++) {
      uint2 u = *(const uint2*)(xb + (size_t)sSrc[kA + i] * 20);
      a0A += bflo(u.x); a1A += bfhi(u.x);
      a2A += bflo(u.y); a3A += bfhi(u.y);
    }
    for (int i = m; i < lenB; i++) {
      uint2 u = *(const uint2*)(xb + (size_t)sSrc[kB + i] * 20);
      a0B += bflo(u.x); a1B += bfhi(u.x);
      a2B += bflo(u.y); a3B += bfhi(u.y);
    }
    float* aA = acc + lnA * AST + c * 4;
    float* aB = acc + lnB * AST + c * 4;
    aA[0] = a0A; aA[1] = a1A; aA[2] = a2A; aA[3] = a3A;
    aB[0] = a0B; aB[1] = a1B; aB[2] = a2B; aB[3] = a3B;
  }
  __syncthreads();

  // dense into registers (acc is still being read), then overwrite acc
  float vreg[8];
#pragma unroll
  for (int u = 0; u < 8; u++) {
    int idx = t + u * 512;
    if (idx < BNODES * HH) {
      int ln = idx / HH;
      int j = idx - ln * HH;
      const float* a = acc + ln * AST;
      const unsigned short* r = roots + ln * DIN;
      float v = sb[j];
#pragma unroll
      for (int f = 0; f < DIN; f++) {
        v += a[f] * sWrel[f * HH + j];
        v += bflo((unsigned)r[f]) * sWroot[f * HH + j];
      }
      vreg[u] = fmaxf(v, 0.0f);
    }
  }
  __syncthreads();
#pragma unroll
  for (int u = 0; u < 8; u++) {
    int idx = t + u * 512;
    if (idx < BNODES * HH) {
      int ln = idx / HH;
      int j = idx - ln * HH;
      acc[ln * AST + j] = vreg[u];
    }
  }
  __syncthreads();

  // block-local pool over the graphs this bucket spans
  int g0 = sBatch[0];
  int g1 = sBatch[BNODES - 1];
  int ngr = g1 - g0 + 1;
  for (int it = t; it < ngr * HH; it += 512) {
    int gi = it / HH;
    int j = it - gi * HH;
    int g = g0 + gi;
    float s = 0.0f, m = 0.0f;
    int c = 0;
    for (int ln = 0; ln < BNODES; ln++) {
      if (sBatch[ln] == g) {
        float v = acc[ln * AST + j];
        s += v;
        m = fmaxf(m, v);
        c++;
      }
    }
    if (c) {
      atomicAdd(&sump[g * HH + j], s);
      atomicMax(&maxp[g * HH + j], __float_as_int(m));
      if (j == 0) atomicAdd(&cnt[g], (float)c);
    }
  }
}

__global__ __launch_bounds__(256) void readout_kernel(
    const float* __restrict__ sump, const int* __restrict__ maxp,
    const float* __restrict__ cnt, const float* __restrict__ Wlin,
    const float* __restrict__ blin, float* __restrict__ out) {
  int idx = blockIdx.x * 256 + threadIdx.x;
  if (idx >= GG * LL) return;
  int g = idx / LL;
  int l = idx - g * LL;
  float c = cnt[g];
  float inv = 1.0f / fmaxf(c, 1.0f);
  float acc = blin[l];
#pragma unroll
  for (int j = 0; j < HH; j++) {
    float mx = __int_as_float(maxp[g * HH + j]);
    float mean = sump[g * HH + j] * inv;
    acc += mx * Wlin[j * LL + l];
    acc += mean * Wlin[(HH + j) * LL + l];
  }
  out[idx] = acc;
}

extern "C" void kernel_launch(void* const* d_in, const int* in_sizes, int n_in,
                              void* d_out, int out_size, void* d_ws,
                              size_t ws_size, hipStream_t stream) {
  const float* x = (const float*)d_in[0];
  const int* edge_index = (const int*)d_in[1];
  const int* batch = (const int*)d_in[2];
  const float* W_rel1 = (const float*)d_in[3];
  const float* b1 = (const float*)d_in[4];
  const float* W_root1 = (const float*)d_in[5];
  const float* W_rel2 = (const float*)d_in[6];
  const float* b2 = (const float*)d_in[7];
  const float* W_root2 = (const float*)d_in[8];
  const float* W_rel3 = (const float*)d_in[9];
  const float* b3 = (const float*)d_in[10];
  const float* W_root3 = (const float*)d_in[11];
  const float* W_lin = (const float*)d_in[12];
  const float* b_lin = (const float*)d_in[13];
  float* out = (float*)d_out;

  const int E = in_sizes[1] / 2;
  const int n_nodes = in_sizes[0] / FF;  // == NN (unused; layout fixed)
  (void)n_nodes;
  const int* src = edge_index;
  const int* dst = edge_index + E;

  // Workspace layout (chunks 16B aligned). cursor..cnt contiguous for one
  // memset: 512 + GG*HH + GG*HH + 512 ints.
  unsigned int* pay = (unsigned int*)d_ws;       // NB*CAP u32 (14.3MB)
  int* cursor = (int*)(pay + (size_t)NB * CAP);  // 512
  float* sump = (float*)(cursor + 512);          // GG*HH
  int* maxp = (int*)(sump + GG * HH);            // GG*HH
  float* cnt = (float*)(maxp + GG * HH);         // 512
  unsigned short* h1 = (unsigned short*)(cnt + 512);  // NN*HH bf16 (4MB)
  unsigned short* h2 = h1 + (size_t)NN * HH;     // NN*HH bf16 (4MB)

  const int edge_tiles = (E + TILE - 1) / TILE;

  // ---- Zero cursors + pool accumulators (one contiguous memset) ----
  hipMemsetAsync(cursor, 0, (size_t)(512 + 2 * GG * HH + 512) * sizeof(int),
                 stream);

  // ---- Edge partition: staged multisplit into fixed bucket regions ----
  multisplit_kernel<<<edge_tiles, 256, 0, stream>>>(src, dst, cursor, pay, E);

  // ---- Fused per-bucket layers (register-accumulated, pair-interleaved) ----
  bucket_layer_kernel<FF, true><<<NB, 512, 0, stream>>>(
      x, pay, cursor, W_rel1, b1, W_root1, h1);
  bucket_layer_kernel<HH, false><<<NB, 512, 0, stream>>>(
      h1, pay, cursor, W_rel2, b2, W_root2, h2);
  bucket_layer_pool_kernel<<<NB, 512, 0, stream>>>(
      h2, pay, cursor, W_rel3, b3, W_root3, batch, sump, maxp, cnt);

  // ---- Readout ----
  readout_kernel<<<(GG * LL + 255) / 256, 256, 0, stream>>>(
      sump, maxp, cnt, W_lin, b_lin, out);
}

// Round 11
// 271.463 us; speedup vs baseline: 1.0087x; 1.0087x over previous
//
#include <hip/hip_runtime.h>
#include <hip/hip_bf16.h>

#define NN 100000   // nodes
#define FF 10       // input features
#define HH 20       // hidden dim
#define GG 512      // graphs
#define LL 2        // labels

#define NB 500      // dst buckets
#define BNODES 200  // nodes per bucket (NN / NB)
#define CAP 7168    // per-bucket capacity (mean 6400, sigma ~80 -> 9.6 sigma)
#define HB 100      // nodes per half-bucket (layer kernels)
#define SCAP 3712   // per-half-bucket edge capacity (mean 3200, ~9 sigma)
#define TILE 4096   // edges per block in multisplit
#define SRC_BITS 17
#define SRC_MASK 0x1FFFFu

// bf16 helpers (storage-only; all math in f32)
__device__ inline unsigned short f2bf(float f) {
  unsigned u = __float_as_uint(f);
  unsigned r = u + 0x7FFFu + ((u >> 16) & 1u);
  return (unsigned short)(r >> 16);
}
__device__ inline float bflo(unsigned u) { return __uint_as_float(u << 16); }
__device__ inline float bfhi(unsigned u) { return __uint_as_float(u & 0xFFFF0000u); }

// ---------------------------------------------------------------------------
// Multisplit (512 thr) with LDS-staged COALESCED writes into fixed-CAP bucket
// regions. Payload pack: (local_dst << 17) | src.
// ---------------------------------------------------------------------------
__global__ __launch_bounds__(512) void multisplit_kernel(
    const int* __restrict__ src, const int* __restrict__ dst,
    int* __restrict__ cursor, unsigned int* __restrict__ pay, int E) {
  __shared__ int lhist[NB];
  __shared__ int lofs[NB];
  __shared__ int gbase[NB];
  __shared__ int lcur[NB];
  __shared__ unsigned int sord[TILE];
  __shared__ unsigned short sdbk[TILE];
  __shared__ int ss[512];
  int t = threadIdx.x;
  if (t < NB) lhist[t] = 0;
  __syncthreads();

  int base = blockIdx.x * TILE;
  int count = E - base;
  if (count > TILE) count = TILE;

  for (int i = t; i < count; i += 512)
    atomicAdd(&lhist[dst[base + i] / BNODES], 1);
  __syncthreads();

  // exclusive scan of lhist (NB=500), 1 elem/thread
  int own = (t < NB) ? lhist[t] : 0;
  ss[t] = own;
  __syncthreads();
  for (int off = 1; off < 512; off <<= 1) {
    int a0 = (t >= off) ? ss[t - off] : 0;
    __syncthreads();
    ss[t] += a0;
    __syncthreads();
  }
  // reserve global ranges (clamped: >9-sigma overflow drops edges, no OOB)
  if (t < NB) {
    lofs[t] = ss[t] - own;
    int bo = own ? atomicAdd(&cursor[t], own) : 0;
    if (bo > CAP - own) bo = CAP - own;
    gbase[t] = t * CAP + bo;
    lcur[t] = 0;
  }
  __syncthreads();

  // pass 2: rank + scatter into bucket-grouped LDS order
  for (int i = t; i < count; i += 512) {
    int e = base + i;
    int d = __builtin_nontemporal_load(dst + e);
    int s = __builtin_nontemporal_load(src + e);
    int bk = d / BNODES;
    int ld = d - bk * BNODES;
    int r = atomicAdd(&lcur[bk], 1);
    int slot = lofs[bk] + r;
    sord[slot] = ((unsigned)ld << SRC_BITS) | (unsigned)s;
    sdbk[slot] = (unsigned short)bk;
  }
  __syncthreads();

  // coalesced run writes
  for (int i = t; i < count; i += 512) {
    int bk = sdbk[i];
    pay[gbase[bk] + (i - lofs[bk])] = sord[i];
  }
}

// ---------------------------------------------------------------------------
// Fused HALF-bucket layer (block b2 owns nodes [b2*100, b2*100+100)):
//  A) two passes over the owning bucket's pay run (25.6KB; 2nd pass L1-hot):
//     hist of own-half edges -> scan -> scatter src into LDS CSR
//  B) gather: task = (local node, chunk); VGPR accumulate; plain LDS store
//  C) dense + bias + root + ReLU from LDS -> bf16 hout
// F32IN: input rows are f32 (layer 1 reads x directly).
// LDS ~33KB -> 4 blocks/CU = 32 waves (full wave occupancy).
// ---------------------------------------------------------------------------
template<int DIN, bool F32IN>
__global__ __launch_bounds__(512) void bucket_layer_kernel(
    const void* __restrict__ hin_v, const unsigned int* __restrict__ pay,
    const int* __restrict__ cursor, const float* __restrict__ Wrel,
    const float* __restrict__ bias, const float* __restrict__ Wroot,
    unsigned short* __restrict__ hout) {
  constexpr int AST = (DIN == 10) ? 11 : 21;  // padded acc stride
  constexpr int CH = DIN / 5;                 // features per chunk (2 or 4)
  __shared__ int sSrc[SCAP];
  __shared__ float acc[HB * AST];
  __shared__ float rootsF[F32IN ? HB * DIN : 1];
  __shared__ unsigned short rootsB[F32IN ? 1 : HB * DIN];
  __shared__ float sWrel[DIN * HH];
  __shared__ float sWroot[DIN * HH];
  __shared__ float sb[HH];
  __shared__ int lhist[HB];
  __shared__ int lcur[HB];
  __shared__ int sRofs[HB];
  __shared__ int sRend[HB];
  __shared__ int ss[128];
  const float* hinF = (const float*)hin_v;
  const unsigned short* hinB = (const unsigned short*)hin_v;
  int b2 = blockIdx.x;
  int bucket = b2 >> 1;
  int lo = (b2 & 1) * HB;       // local node offset within bucket
  int t = threadIdx.x;
  int nbase = b2 * HB;          // global node base

  for (int i = t; i < DIN * HH; i += 512) {
    sWrel[i] = Wrel[i];
    sWroot[i] = Wroot[i];
  }
  if (t < HH) sb[t] = bias[t];
  if (t < HB) lhist[t] = 0;
  if (F32IN) {
    const float* rs = hinF + (size_t)nbase * DIN;
    for (int i = t; i < HB * DIN; i += 512) rootsF[i] = rs[i];
  } else {
    const unsigned* rs = (const unsigned*)(hinB + (size_t)nbase * DIN);
    unsigned* rd = (unsigned*)rootsB;
    for (int i = t; i < HB * DIN / 2; i += 512) rd[i] = rs[i];
  }
  __syncthreads();

  int ecnt = cursor[bucket];
  if (ecnt > CAP) ecnt = CAP;
  const unsigned int* mypay = pay + (size_t)bucket * CAP;

  // A1: histogram of own-half edges
  for (int i = t; i < ecnt; i += 512) {
    int ld = (int)(mypay[i] >> SRC_BITS) - lo;
    if ((unsigned)ld < HB) atomicAdd(&lhist[ld], 1);
  }
  __syncthreads();

  // A2: scan (100 entries, first 128 threads)
  int own = (t < HB) ? lhist[t] : 0;
  if (t < 128) ss[t] = own;
  __syncthreads();
  for (int off = 1; off < 128; off <<= 1) {
    int a0 = (t < 128 && t >= off) ? ss[t - off] : 0;
    __syncthreads();
    if (t < 128) ss[t] += a0;
    __syncthreads();
  }
  if (t < HB) {
    int ex = ss[t] - own;
    sRofs[t] = ex;
    int en = ex + own;
    sRend[t] = en < SCAP ? en : SCAP;
    lcur[t] = 0;
  }
  __syncthreads();

  // A3: scatter src into node-sorted LDS order (pay run now L1-hot)
  for (int i = t; i < ecnt; i += 512) {
    unsigned p = mypay[i];
    int ld = (int)(p >> SRC_BITS) - lo;
    if ((unsigned)ld < HB) {
      int r = atomicAdd(&lcur[ld], 1);
      int slot = sRofs[ld] + r;
      if (slot < SCAP) sSrc[slot] = (int)(p & SRC_MASK);
    }
  }
  __syncthreads();

  // B: gather with register accumulation (task = node x chunk)
  if (t < HB * 5) {
    int ln = t / 5;
    int c = t - ln * 5;
    int k0 = sRofs[ln], k1 = sRend[ln];
    float a0 = 0, a1 = 0, a2 = 0, a3 = 0;
    if (F32IN) {
      const float* xb = hinF + c * CH;
      for (int k = k0; k < k1; k++) {
        float2 v = *(const float2*)(xb + (size_t)sSrc[k] * DIN);
        a0 += v.x;
        a1 += v.y;
      }
    } else {
      const unsigned short* xb = hinB + c * CH;
      for (int k = k0; k < k1; k++) {
        uint2 u = *(const uint2*)(xb + (size_t)sSrc[k] * DIN);
        a0 += bflo(u.x);
        a1 += bfhi(u.x);
        a2 += bflo(u.y);
        a3 += bfhi(u.y);
      }
    }
    float* a = acc + ln * AST + c * CH;
    if (CH == 4) {
      a[0] = a0; a[1] = a1; a[2] = a2; a[3] = a3;
    } else {
      a[0] = a0; a[1] = a1;
    }
  }
  __syncthreads();

  // C: dense + bias + root + relu -> global bf16
  for (int idx = t; idx < HB * HH; idx += 512) {
    int ln = idx / HH;
    int j = idx - ln * HH;
    const float* a = acc + ln * AST;
    float v = sb[j];
#pragma unroll
    for (int f = 0; f < DIN; f++) {
      float rv = F32IN ? rootsF[ln * DIN + f] : bflo((unsigned)rootsB[ln * DIN + f]);
      v += a[f] * sWrel[f * HH + j];
      v += rv * sWroot[f * HH + j];
    }
    hout[(size_t)nbase * HH + idx] = f2bf(fmaxf(v, 0.0f));
  }
}

// ---------------------------------------------------------------------------
// Layer 3 + pooling (half-bucket): dense staged in registers then written
// over acc (dead), then block-local pool + few global atomics.
// Post-ReLU >= 0 -> int atomicMax on float bits order-correct; zero init
// reproduces where(cnt>0, max, 0).
// ---------------------------------------------------------------------------
__global__ __launch_bounds__(512) void bucket_layer_pool_kernel(
    const unsigned short* __restrict__ hin, const unsigned int* __restrict__ pay,
    const int* __restrict__ cursor, const float* __restrict__ Wrel,
    const float* __restrict__ bias, const float* __restrict__ Wroot,
    const int* __restrict__ batch, float* __restrict__ sump,
    int* __restrict__ maxp, float* __restrict__ cnt) {
  constexpr int DIN = 20;
  constexpr int AST = 21;
  __shared__ int sSrc[SCAP];
  __shared__ float acc[HB * AST];
  __shared__ unsigned short roots[HB * DIN];
  __shared__ int sBatch[HB];
  __shared__ float sWrel[DIN * HH];
  __shared__ float sWroot[DIN * HH];
  __shared__ float sb[HH];
  __shared__ int lhist[HB];
  __shared__ int lcur[HB];
  __shared__ int sRofs[HB];
  __shared__ int sRend[HB];
  __shared__ int ss[128];
  int b2 = blockIdx.x;
  int bucket = b2 >> 1;
  int lo = (b2 & 1) * HB;
  int t = threadIdx.x;
  int nbase = b2 * HB;

  for (int i = t; i < DIN * HH; i += 512) {
    sWrel[i] = Wrel[i];
    sWroot[i] = Wroot[i];
  }
  if (t < HH) sb[t] = bias[t];
  if (t < HB) {
    lhist[t] = 0;
    sBatch[t] = batch[nbase + t];
  }
  {
    const unsigned* rs = (const unsigned*)(hin + (size_t)nbase * DIN);
    unsigned* rd = (unsigned*)roots;
    for (int i = t; i < HB * DIN / 2; i += 512) rd[i] = rs[i];
  }
  __syncthreads();

  int ecnt = cursor[bucket];
  if (ecnt > CAP) ecnt = CAP;
  const unsigned int* mypay = pay + (size_t)bucket * CAP;

  for (int i = t; i < ecnt; i += 512) {
    int ld = (int)(mypay[i] >> SRC_BITS) - lo;
    if ((unsigned)ld < HB) atomicAdd(&lhist[ld], 1);
  }
  __syncthreads();

  int own = (t < HB) ? lhist[t] : 0;
  if (t < 128) ss[t] = own;
  __syncthreads();
  for (int off = 1; off < 128; off <<= 1) {
    int a0 = (t < 128 && t >= off) ? ss[t - off] : 0;
    __syncthreads();
    if (t < 128) ss[t] += a0;
    __syncthreads();
  }
  if (t < HB) {
    int ex = ss[t] - own;
    sRofs[t] = ex;
    int en = ex + own;
    sRend[t] = en < SCAP ? en : SCAP;
    lcur[t] = 0;
  }
  __syncthreads();

  for (int i = t; i < ecnt; i += 512) {
    unsigned p = mypay[i];
    int ld = (int)(p >> SRC_BITS) - lo;
    if ((unsigned)ld < HB) {
      int r = atomicAdd(&lcur[ld], 1);
      int slot = sRofs[ld] + r;
      if (slot < SCAP) sSrc[slot] = (int)(p & SRC_MASK);
    }
  }
  __syncthreads();

  if (t < HB * 5) {
    int ln = t / 5;
    int c = t - ln * 5;
    int k0 = sRofs[ln], k1 = sRend[ln];
    float a0 = 0, a1 = 0, a2 = 0, a3 = 0;
    const unsigned short* xb = hin + c * 4;
    for (int k = k0; k < k1; k++) {
      uint2 u = *(const uint2*)(xb + (size_t)sSrc[k] * 20);
      a0 += bflo(u.x);
      a1 += bfhi(u.x);
      a2 += bflo(u.y);
      a3 += bfhi(u.y);
    }
    float* a = acc + ln * AST + c * 4;
    a[0] = a0; a[1] = a1; a[2] = a2; a[3] = a3;
  }
  __syncthreads();

  // dense into registers (acc is still being read), then overwrite acc
  float vreg[4];
#pragma unroll
  for (int u = 0; u < 4; u++) {
    int idx = t + u * 512;
    if (idx < HB * HH) {
      int ln = idx / HH;
      int j = idx - ln * HH;
      const float* a = acc + ln * AST;
      const unsigned short* r = roots + ln * DIN;
      float v = sb[j];
#pragma unroll
      for (int f = 0; f < DIN; f++) {
        v += a[f] * sWrel[f * HH + j];
        v += bflo((unsigned)r[f]) * sWroot[f * HH + j];
      }
      vreg[u] = fmaxf(v, 0.0f);
    }
  }
  __syncthreads();
#pragma unroll
  for (int u = 0; u < 4; u++) {
    int idx = t + u * 512;
    if (idx < HB * HH) {
      int ln = idx / HH;
      int j = idx - ln * HH;
      acc[ln * AST + j] = vreg[u];
    }
  }
  __syncthreads();

  // block-local pool over the graphs this half-bucket spans
  int g0 = sBatch[0];
  int g1 = sBatch[HB - 1];
  int ngr = g1 - g0 + 1;
  for (int it = t; it < ngr * HH; it += 512) {
    int gi = it / HH;
    int j = it - gi * HH;
    int g = g0 + gi;
    float s = 0.0f, m = 0.0f;
    int c = 0;
    for (int ln = 0; ln < HB; ln++) {
      if (sBatch[ln] == g) {
        float v = acc[ln * AST + j];
        s += v;
        m = fmaxf(m, v);
        c++;
      }
    }
    if (c) {
      atomicAdd(&sump[g * HH + j], s);
      atomicMax(&maxp[g * HH + j], __float_as_int(m));
      if (j == 0) atomicAdd(&cnt[g], (float)c);
    }
  }
}

__global__ __launch_bounds__(256) void readout_kernel(
    const float* __restrict__ sump, const int* __restrict__ maxp,
    const float* __restrict__ cnt, const float* __restrict__ Wlin,
    const float* __restrict__ blin, float* __restrict__ out) {
  int idx = blockIdx.x * 256 + threadIdx.x;
  if (idx >= GG * LL) return;
  int g = idx / LL;
  int l = idx - g * LL;
  float c = cnt[g];
  float inv = 1.0f / fmaxf(c, 1.0f);
  float acc = blin[l];
#pragma unroll
  for (int j = 0; j < HH; j++) {
    float mx = __int_as_float(maxp[g * HH + j]);
    float mean = sump[g * HH + j] * inv;
    acc += mx * Wlin[j * LL + l];
    acc += mean * Wlin[(HH + j) * LL + l];
  }
  out[idx] = acc;
}

extern "C" void kernel_launch(void* const* d_in, const int* in_sizes, int n_in,
                              void* d_out, int out_size, void* d_ws,
                              size_t ws_size, hipStream_t stream) {
  const float* x = (const float*)d_in[0];
  const int* edge_index = (const int*)d_in[1];
  const int* batch = (const int*)d_in[2];
  const float* W_rel1 = (const float*)d_in[3];
  const float* b1 = (const float*)d_in[4];
  const float* W_root1 = (const float*)d_in[5];
  const float* W_rel2 = (const float*)d_in[6];
  const float* b2 = (const float*)d_in[7];
  const float* W_root2 = (const float*)d_in[8];
  const float* W_rel3 = (const float*)d_in[9];
  const float* b3 = (const float*)d_in[10];
  const float* W_root3 = (const float*)d_in[11];
  const float* W_lin = (const float*)d_in[12];
  const float* b_lin = (const float*)d_in[13];
  float* out = (float*)d_out;

  const int E = in_sizes[1] / 2;
  const int* src = edge_index;
  const int* dst = edge_index + E;

  // Workspace layout (chunks 16B aligned). cursor..cnt contiguous for one
  // memset: 512 + GG*HH + GG*HH + 512 ints.
  unsigned int* pay = (unsigned int*)d_ws;       // NB*CAP u32 (14.3MB)
  int* cursor = (int*)(pay + (size_t)NB * CAP);  // 512
  float* sump = (float*)(cursor + 512);          // GG*HH
  int* maxp = (int*)(sump + GG * HH);            // GG*HH
  float* cnt = (float*)(maxp + GG * HH);         // 512
  unsigned short* h1 = (unsigned short*)(cnt + 512);  // NN*HH bf16 (4MB)
  unsigned short* h2 = h1 + (size_t)NN * HH;     // NN*HH bf16 (4MB)

  const int edge_tiles = (E + TILE - 1) / TILE;

  // ---- Zero cursors + pool accumulators (one contiguous memset) ----
  hipMemsetAsync(cursor, 0, (size_t)(512 + 2 * GG * HH + 512) * sizeof(int),
                 stream);

  // ---- Edge partition: staged multisplit into fixed bucket regions ----
  multisplit_kernel<<<edge_tiles, 512, 0, stream>>>(src, dst, cursor, pay, E);

  // ---- Fused per-half-bucket layers (register-accumulated) ----
  bucket_layer_kernel<FF, true><<<NB * 2, 512, 0, stream>>>(
      x, pay, cursor, W_rel1, b1, W_root1, h1);
  bucket_layer_kernel<HH, false><<<NB * 2, 512, 0, stream>>>(
      h1, pay, cursor, W_rel2, b2, W_root2, h2);
  bucket_layer_pool_kernel<<<NB * 2, 512, 0, stream>>>(
      h2, pay, cursor, W_rel3, b3, W_root3, batch, sump, maxp, cnt);

  // ---- Readout ----
  readout_kernel<<<(GG * LL + 255) / 256, 256, 0, stream>>>(
      sump, maxp, cnt, W_lin, b_lin, out);
}